// Round 1
// baseline (605.094 us; speedup 1.0000x reference)
//
#include <hip/hip_runtime.h>
#include <hip/hip_fp16.h>
#include <cstdint>
#include <cstddef>

typedef _Float16 f16;
typedef _Float16 half8 __attribute__((ext_vector_type(8)));
typedef _Float16 half4v __attribute__((ext_vector_type(4)));
typedef float floatx4 __attribute__((ext_vector_type(4)));

#define MTOT 49152  // B*T*HW rows total (=2*96*256), also = N_TOT*T

// ---------------------------------------------------------------------------
// async global->LDS, 16B per lane
__device__ __forceinline__ void gload_lds16(const f16* g, f16* l) {
  __builtin_amdgcn_global_load_lds((const __attribute__((address_space(1))) void*)g,
                                   (__attribute__((address_space(3))) void*)l, 16, 0, 0);
}

// ---------------------------------------------------------------------------
// Convert weights fp32 -> f16. WQKV rows: [0,512)=Wq [512,1024)=Wk
// [1024,1536)=Wkl [1536,2048)=Wvl [2048,2560)=Wv.  WO separate.
__global__ __launch_bounds__(256) void wconv_kernel(
    const float* __restrict__ Wq, const float* __restrict__ Wk,
    const float* __restrict__ Wv, const float* __restrict__ Wkl,
    const float* __restrict__ Wvl, const float* __restrict__ Wo,
    f16* __restrict__ WQKV, f16* __restrict__ WO) {
  int idx = blockIdx.x * 256 + threadIdx.x;
  if (idx < 2560 * 512) {
    int row = idx >> 9;
    int col = idx & 511;
    int seg = row >> 9;
    int r = row & 511;
    const float* src;
    switch (seg) {
      case 0: src = Wq; break;
      case 1: src = Wk; break;
      case 2: src = Wkl; break;
      case 3: src = Wvl; break;
      default: src = Wv; break;
    }
    WQKV[idx] = (f16)src[r * 512 + col];
  }
  if (idx < 512 * 512) WO[idx] = (f16)Wo[idx];
}

// ---------------------------------------------------------------------------
// LayerNorm over D. x layout (B=2, D=512, T=96, HW=256).
// Output XN f16 row-major [m][512], m = (b*256+hw)*96 + t.
__global__ __launch_bounds__(256) void ln_kernel(
    const float* __restrict__ x, const float* __restrict__ gamma,
    const float* __restrict__ beta, f16* __restrict__ XN) {
  const int b = blockIdx.x / 96;
  const int t = blockIdx.x % 96;
  const int hw = threadIdx.x;
  const float* xp = x + (size_t)b * 512 * 96 * 256 + (size_t)t * 256 + hw;
  float s = 0.f, s2 = 0.f;
  for (int d = 0; d < 512; ++d) {
    float v = xp[(size_t)d * 96 * 256];
    s += v;
    s2 += v * v;
  }
  const float mean = s * (1.f / 512.f);
  float var = s2 * (1.f / 512.f) - mean * mean;
  var = fmaxf(var, 0.f);
  const float rstd = rsqrtf(var + 1e-6f);
  const int n = b * 256 + hw;
  f16* outp = XN + ((size_t)n * 96 + t) * 512;
  for (int d0 = 0; d0 < 512; d0 += 8) {
    half8 buf;
#pragma unroll
    for (int j = 0; j < 8; ++j) {
      float v = xp[(size_t)(d0 + j) * 96 * 256];
      buf[j] = (f16)((v - mean) * rstd * gamma[d0 + j] + beta[d0 + j]);
    }
    *(half8*)(outp + d0) = buf;
  }
}

// ---------------------------------------------------------------------------
// Tiled f16 GEMM: C[m][n] = sum_k A[m][k]*B[n][k]  (K=512 fixed)
// BM=BN=128, BK=32, 4 waves (2x2), wave tile 64x64 of 16x16x32 MFMA.
// EPI==0: GEMM1 epilogue (QKV chunk f16, V transposed into VT, q-bias on n<512)
// EPI==1: GEMM2 epilogue (fp32 out in (B,D,T,HW) layout; GEMM-N = row index m2)
template <int EPI>
__global__ __launch_bounds__(256) void gemm_kernel(
    const f16* __restrict__ A, const f16* __restrict__ B,
    f16* __restrict__ Cqkv, f16* __restrict__ VT,
    const float* __restrict__ qbias, float* __restrict__ Out) {
  __shared__ f16 As[128 * 32];
  __shared__ f16 Bs[128 * 32];
  const int m0 = blockIdx.x * 128;
  const int n0 = blockIdx.y * 128;
  const int tid = threadIdx.x;
  const int lane = tid & 63;
  const int wid = tid >> 6;
  const int wm = wid >> 1, wn = wid & 1;
  const int l15 = lane & 15, l4 = lane >> 4;

  floatx4 acc[4][4] = {};

  const int srow = tid >> 2;
  const int skp = (tid & 3) * 8;
  const f16* ap = A + (size_t)(m0 + srow) * 512 + skp;
  const f16* bp = B + (size_t)(n0 + srow) * 512 + skp;
  f16* asl = As + tid * 8;
  f16* bsl = Bs + tid * 8;

  for (int k0 = 0; k0 < 512; k0 += 32) {
    gload_lds16(ap + k0, asl);
    gload_lds16(ap + (size_t)64 * 512 + k0, asl + 2048);
    gload_lds16(bp + k0, bsl);
    gload_lds16(bp + (size_t)64 * 512 + k0, bsl + 2048);
    __syncthreads();
    half8 af[4], bf[4];
#pragma unroll
    for (int mf = 0; mf < 4; ++mf)
      af[mf] = *(const half8*)(As + (wm * 64 + mf * 16 + l15) * 32 + l4 * 8);
#pragma unroll
    for (int nf = 0; nf < 4; ++nf)
      bf[nf] = *(const half8*)(Bs + (wn * 64 + nf * 16 + l15) * 32 + l4 * 8);
#pragma unroll
    for (int mf = 0; mf < 4; ++mf)
#pragma unroll
      for (int nf = 0; nf < 4; ++nf)
        acc[mf][nf] = __builtin_amdgcn_mfma_f32_16x16x32_f16(af[mf], bf[nf], acc[mf][nf], 0, 0, 0);
    __syncthreads();
  }

  const int mbase = m0 + wm * 64;
  const int nbase = n0 + wn * 64;
  if (EPI == 0) {
#pragma unroll
    for (int nf = 0; nf < 4; ++nf) {
      const int n = nbase + nf * 16 + l15;
      if (n < 2048) {
        const float bias = (n < 512) ? qbias[n] : 0.0f;
#pragma unroll
        for (int mf = 0; mf < 4; ++mf) {
          const int mr = mbase + mf * 16 + l4 * 4;
#pragma unroll
          for (int j = 0; j < 4; ++j)
            Cqkv[(size_t)(mr + j) * 2048 + n] = (f16)(acc[mf][nf][j] + bias);
        }
      } else {
        const int i = n - 2048;
#pragma unroll
        for (int mf = 0; mf < 4; ++mf) {
          const int mr = mbase + mf * 16 + l4 * 4;
          const int nn = mr / 96;
          const int t = mr % 96;
          half4v v;
#pragma unroll
          for (int j = 0; j < 4; ++j) v[j] = (f16)acc[mf][nf][j];
          *(half4v*)(VT + ((size_t)nn * 512 + i) * 96 + t) = v;
        }
      }
    }
  } else {
#pragma unroll
    for (int nf = 0; nf < 4; ++nf) {
      const int m2 = nbase + nf * 16 + l15;
      const int bb = m2 / 24576;
      const int rem = m2 - bb * 24576;
      const int t = rem >> 8;
      const int hw = rem & 255;
      float* op = Out + ((size_t)bb * 512 * 96 + t) * 256 + hw;
#pragma unroll
      for (int mf = 0; mf < 4; ++mf) {
#pragma unroll
        for (int j = 0; j < 4; ++j) {
          const int d = mbase + mf * 16 + l4 * 4 + j;
          op[(size_t)d * 96 * 256] = acc[mf][nf][j];
        }
      }
    }
  }
}

// ---------------------------------------------------------------------------
// Attention: one wave per (n, head). T=96 queries/keys, dh=64, local band s=3.
// QKV chunk rows m=(nn*96+t), cols: [0,512)=Q(+bias) [512,1024)=K
// [1024,1536)=KL [1536,2048)=VL. VT[nn][512][96] = V transposed.
__global__ __launch_bounds__(64) void attn_kernel(
    const f16* __restrict__ QKV, const f16* __restrict__ VT,
    f16* __restrict__ AO, int n0chunk) {
  const int nn = blockIdx.x >> 3;
  const int h = blockIdx.x & 7;
  const int lane = threadIdx.x;
  const int l15 = lane & 15, l4 = lane >> 4;
  const int nglob = n0chunk + nn;
  const int bb = nglob >> 8, hw = nglob & 255;

  __shared__ float locS[16][4];
  __shared__ float alS[16][4];
  __shared__ f16 pS[16][104];

  const f16* base = QKV + (size_t)nn * 96 * 2048;

  // K fragments (B operand of QK^T): col t' = l15 + nf*16, k = i
  half8 kb[6][2];
#pragma unroll
  for (int nf = 0; nf < 6; ++nf)
#pragma unroll
    for (int kg = 0; kg < 2; ++kg)
      kb[nf][kg] = *(const half8*)(base + (size_t)(nf * 16 + l15) * 2048 + 512 + h * 64 + kg * 32 + l4 * 8);

  // V fragments (B operand of P@V): col i = l15 + nf*16, k = g
  half8 vb[4][3];
  const f16* vtb = VT + ((size_t)nn * 512 + h * 64) * 96;
#pragma unroll
  for (int nf = 0; nf < 4; ++nf)
#pragma unroll
    for (int kg = 0; kg < 3; ++kg)
      vb[nf][kg] = *(const half8*)(vtb + (size_t)(nf * 16 + l15) * 96 + kg * 32 + l4 * 8);

  for (int mb = 0; mb < 6; ++mb) {
    const int t0 = mb * 16;

    // ---- local band logits (48 lanes, f32 dot-64) -> locS
    {
      const int tl = lane >> 2, sel = lane & 3;
      if (sel < 3) {
        const int t = t0 + tl;
        const int tp = t + sel - 1;
        float v = -INFINITY;
        if (tp >= 0 && tp < 96) {
          const f16* qr = base + (size_t)t * 2048 + h * 64;
          const f16* kr = base + (size_t)tp * 2048 + 1024 + h * 64;
          float a = 0.f;
#pragma unroll
          for (int w = 0; w < 8; ++w) {
            half8 qv = *(const half8*)(qr + w * 8);
            half8 kv = *(const half8*)(kr + w * 8);
#pragma unroll
            for (int e = 0; e < 8; ++e) a += (float)qv[e] * (float)kv[e];
          }
          v = a * 0.125f;
        }
        locS[tl][sel] = v;
      }
    }

    // ---- S = Q K^T (16 rows x 96 cols)
    floatx4 s[6] = {};
    half8 aq[2];
#pragma unroll
    for (int kg = 0; kg < 2; ++kg)
      aq[kg] = *(const half8*)(base + (size_t)(t0 + l15) * 2048 + h * 64 + kg * 32 + l4 * 8);
#pragma unroll
    for (int nf = 0; nf < 6; ++nf)
#pragma unroll
      for (int kg = 0; kg < 2; ++kg)
        s[nf] = __builtin_amdgcn_mfma_f32_16x16x32_f16(aq[kg], kb[nf][kg], s[nf], 0, 0, 0);
#pragma unroll
    for (int nf = 0; nf < 6; ++nf) s[nf] = s[nf] * 0.125f;

    __syncthreads();  // locS visible

    // ---- softmax per row (C-layout: row = l4*4+j, col = l15 + nf*16)
#pragma unroll
    for (int j = 0; j < 4; ++j) {
      const int row = l4 * 4 + j;
      float sv[6];
#pragma unroll
      for (int nf = 0; nf < 6; ++nf) sv[nf] = s[nf][j];
      float mx = sv[0];
#pragma unroll
      for (int nf = 1; nf < 6; ++nf) mx = fmaxf(mx, sv[nf]);
      for (int off = 1; off < 16; off <<= 1) mx = fmaxf(mx, __shfl_xor(mx, off, 64));
      const float l0 = locS[row][0], l1 = locS[row][1], l2 = locS[row][2];
      mx = fmaxf(mx, fmaxf(l0, fmaxf(l1, l2)));
      float e[6], sum = 0.f;
#pragma unroll
      for (int nf = 0; nf < 6; ++nf) {
        e[nf] = expf(sv[nf] - mx);
        sum += e[nf];
      }
      for (int off = 1; off < 16; off <<= 1) sum += __shfl_xor(sum, off, 64);
      const float e0 = expf(l0 - mx), e1 = expf(l1 - mx), e2 = expf(l2 - mx);
      sum += e0 + e1 + e2;
      const float rd = 1.0f / sum;
#pragma unroll
      for (int nf = 0; nf < 6; ++nf) pS[row][nf * 16 + l15] = (f16)(e[nf] * rd);
      if (l15 < 3) alS[row][l15] = (l15 == 0 ? e0 : (l15 == 1 ? e1 : e2)) * rd;
    }

    __syncthreads();  // pS / alS visible

    // ---- O = P @ V
    floatx4 o[4] = {};
    half8 pfr[3];
#pragma unroll
    for (int kg = 0; kg < 3; ++kg)
      pfr[kg] = *(const half8*)(&pS[l15][kg * 32 + l4 * 8]);
#pragma unroll
    for (int nf = 0; nf < 4; ++nf)
#pragma unroll
      for (int kg = 0; kg < 3; ++kg)
        o[nf] = __builtin_amdgcn_mfma_f32_16x16x32_f16(pfr[kg], vb[nf][kg], o[nf], 0, 0, 0);

    // ---- add local band (x_local) and store
#pragma unroll
    for (int nf = 0; nf < 4; ++nf) {
      const int col = h * 64 + nf * 16 + l15;
#pragma unroll
      for (int j = 0; j < 4; ++j) {
        const int row = l4 * 4 + j;
        const int t = t0 + row;
        float xv = o[nf][j];
#pragma unroll
        for (int sel = 0; sel < 3; ++sel) {
          const int tp = t + sel - 1;
          if (tp >= 0 && tp < 96) {
            xv += alS[row][sel] * (float)base[(size_t)tp * 2048 + 1536 + col];
          }
        }
        AO[((size_t)(bb * 96 + t) * 256 + hw) * 512 + col] = (f16)xv;
      }
    }
    __syncthreads();  // protect LDS for next m-block
  }
}

// ---------------------------------------------------------------------------
extern "C" void kernel_launch(void* const* d_in, const int* in_sizes, int n_in,
                              void* d_out, int out_size, void* d_ws, size_t ws_size,
                              hipStream_t stream) {
  (void)in_sizes; (void)n_in; (void)out_size;
  const float* x     = (const float*)d_in[0];
  const float* gamma = (const float*)d_in[1];
  const float* beta  = (const float*)d_in[2];
  const float* Wq    = (const float*)d_in[3];
  const float* Wk    = (const float*)d_in[4];
  const float* Wv    = (const float*)d_in[5];
  const float* Wkl   = (const float*)d_in[6];
  const float* Wvl   = (const float*)d_in[7];
  const float* Wo    = (const float*)d_in[8];
  const float* qb    = (const float*)d_in[9];
  float* out = (float*)d_out;

  char* ws = (char*)d_ws;
  size_t off = 0;
  auto alloc = [&](size_t bytes) -> void* {
    void* p = ws + off;
    off += (bytes + 255) & ~(size_t)255;
    return p;
  };
  f16* XN   = (f16*)alloc((size_t)MTOT * 512 * 2);
  f16* AO   = (f16*)alloc((size_t)MTOT * 512 * 2);
  f16* WQKV = (f16*)alloc((size_t)2560 * 512 * 2);
  f16* WOh  = (f16*)alloc((size_t)512 * 512 * 2);
  // chunking over n (512 total) to bound workspace
  int cn = 512;
  while (cn > 4 &&
         off + (size_t)cn * 96 * 2048 * 2 + 256 + (size_t)cn * 512 * 96 * 2 + 256 > ws_size)
    cn >>= 1;
  f16* QKVc = (f16*)alloc((size_t)cn * 96 * 2048 * 2);
  f16* VTc  = (f16*)alloc((size_t)cn * 512 * 96 * 2);

  wconv_kernel<<<5120, 256, 0, stream>>>(Wq, Wk, Wv, Wkl, Wvl, Wo, WQKV, WOh);
  ln_kernel<<<192, 256, 0, stream>>>(x, gamma, beta, XN);

  const int nch = 512 / cn;
  for (int c = 0; c < nch; ++c) {
    dim3 g1(cn * 96 / 128, 20);
    gemm_kernel<0><<<g1, 256, 0, stream>>>(XN + (size_t)c * cn * 96 * 512, WQKV,
                                           QKVc, VTc, qb, nullptr);
    attn_kernel<<<cn * 8, 64, 0, stream>>>(QKVc, VTc, AO, c * cn);
  }
  gemm_kernel<1><<<dim3(4, 384), 256, 0, stream>>>(WOh, AO, nullptr, nullptr, nullptr, out);
}

// Round 2
// 538.929 us; speedup vs baseline: 1.1228x; 1.1228x over previous
//
#include <hip/hip_runtime.h>
#include <hip/hip_fp16.h>
#include <cstdint>
#include <cstddef>

typedef _Float16 f16;
typedef _Float16 half8 __attribute__((ext_vector_type(8)));
typedef _Float16 half4v __attribute__((ext_vector_type(4)));
typedef float floatx4 __attribute__((ext_vector_type(4)));

#define MTOT 49152  // B*T*HW rows total (=2*96*256), also = N_TOT*T

// ---------------------------------------------------------------------------
// async global->LDS, 16B per lane
__device__ __forceinline__ void gload_lds16(const f16* g, f16* l) {
  __builtin_amdgcn_global_load_lds((const __attribute__((address_space(1))) void*)g,
                                   (__attribute__((address_space(3))) void*)l, 16, 0, 0);
}

// ---------------------------------------------------------------------------
// Convert weights fp32 -> f16. WQKV rows: [0,512)=Wq [512,1024)=Wk
// [1024,1536)=Wkl [1536,2048)=Wvl [2048,2560)=Wv.  WO separate.
__global__ __launch_bounds__(256) void wconv_kernel(
    const float* __restrict__ Wq, const float* __restrict__ Wk,
    const float* __restrict__ Wv, const float* __restrict__ Wkl,
    const float* __restrict__ Wvl, const float* __restrict__ Wo,
    f16* __restrict__ WQKV, f16* __restrict__ WO) {
  int idx = blockIdx.x * 256 + threadIdx.x;
  if (idx < 2560 * 512) {
    int row = idx >> 9;
    int col = idx & 511;
    int seg = row >> 9;
    int r = row & 511;
    const float* src;
    switch (seg) {
      case 0: src = Wq; break;
      case 1: src = Wk; break;
      case 2: src = Wkl; break;
      case 3: src = Wvl; break;
      default: src = Wv; break;
    }
    WQKV[idx] = (f16)src[r * 512 + col];
  }
  if (idx < 512 * 512) WO[idx] = (f16)Wo[idx];
}

// ---------------------------------------------------------------------------
// LayerNorm over D. x layout (B=2, D=512, T=96, HW=256).
// Output XN f16 row-major [m][512], m = (b*256+hw)*96 + t.
// grid = 2*96*4 blocks; block = 256 threads = 64 hw-lanes x 4 d-groups.
__global__ __launch_bounds__(256) void ln_kernel(
    const float* __restrict__ x, const float* __restrict__ gamma,
    const float* __restrict__ beta, f16* __restrict__ XN) {
  const int hwg = blockIdx.x & 3;
  const int t   = (blockIdx.x >> 2) % 96;
  const int b   = blockIdx.x / (4 * 96);
  const int lhw = threadIdx.x & 63;
  const int dg  = threadIdx.x >> 6;
  const int hw  = hwg * 64 + lhw;
  const float* xp = x + (size_t)b * 512 * 24576 + (size_t)t * 256 + hw;

  float s = 0.f, s2 = 0.f;
  for (int d = dg * 128; d < dg * 128 + 128; ++d) {
    float v = xp[(size_t)d * 24576];
    s += v;
    s2 += v * v;
  }
  __shared__ float S1[4][64], S2[4][64];
  S1[dg][lhw] = s;
  S2[dg][lhw] = s2;
  __syncthreads();
  s  = S1[0][lhw] + S1[1][lhw] + S1[2][lhw] + S1[3][lhw];
  s2 = S2[0][lhw] + S2[1][lhw] + S2[2][lhw] + S2[3][lhw];
  const float mean = s * (1.f / 512.f);
  float var = s2 * (1.f / 512.f) - mean * mean;
  var = fmaxf(var, 0.f);
  const float rstd = rsqrtf(var + 1e-6f);
  const int n = b * 256 + hw;
  f16* outp = XN + ((size_t)n * 96 + t) * 512;
  for (int d0 = dg * 128; d0 < dg * 128 + 128; d0 += 8) {
    half8 buf;
#pragma unroll
    for (int j = 0; j < 8; ++j) {
      float v = xp[(size_t)(d0 + j) * 24576];
      buf[j] = (f16)((v - mean) * rstd * gamma[d0 + j] + beta[d0 + j]);
    }
    *(half8*)(outp + d0) = buf;
  }
}

// ---------------------------------------------------------------------------
// Tiled f16 GEMM: C[m][n] = sum_k A[m][k]*B[n][k]  (K=512 fixed)
// BM=BN=128, BK=32, 4 waves (2x2), wave tile 64x64 of 16x16x32 MFMA.
// Double-buffered LDS, single barrier per K-step (stage next before compute).
// 1D grid with XCD-chunked, reuse-ordered tile mapping:
//   EPI==0: tiles = (mtiles x 20 ntiles), n-tile INNER  -> A panel L2 reuse
//   EPI==1: tiles = (4 mtiles x 384 ntiles), m-tile INNER -> B panel L2 reuse
template <int EPI>
__global__ __launch_bounds__(256) void gemm_kernel(
    const f16* __restrict__ A, const f16* __restrict__ B,
    f16* __restrict__ Cqkv, f16* __restrict__ VT,
    const float* __restrict__ qbias, float* __restrict__ Out) {
  __shared__ f16 As[2][128 * 32];
  __shared__ f16 Bs[2][128 * 32];

  const int lin = blockIdx.x;
  const int cpx = (int)gridDim.x >> 3;  // per-XCD chunk (gridDim.x % 8 == 0)
  const int o = (lin & 7) * cpx + (lin >> 3);
  int mt, nt;
  if (EPI == 0) {
    mt = o / 20;
    nt = o % 20;
  } else {
    nt = o >> 2;
    mt = o & 3;
  }
  const int m0 = mt * 128;
  const int n0 = nt * 128;
  const int tid = threadIdx.x;
  const int lane = tid & 63;
  const int wid = tid >> 6;
  const int wm = wid >> 1, wn = wid & 1;
  const int l15 = lane & 15, l4 = lane >> 4;

  floatx4 acc[4][4] = {};

  const int srow = tid >> 2;
  const int skp = (tid & 3) * 8;
  const f16* ap = A + (size_t)(m0 + srow) * 512 + skp;
  const f16* bp = B + (size_t)(n0 + srow) * 512 + skp;

  auto stage = [&](int buf, int k0) {
    f16* asl = As[buf] + tid * 8;
    f16* bsl = Bs[buf] + tid * 8;
    gload_lds16(ap + k0, asl);
    gload_lds16(ap + (size_t)64 * 512 + k0, asl + 2048);
    gload_lds16(bp + k0, bsl);
    gload_lds16(bp + (size_t)64 * 512 + k0, bsl + 2048);
  };

  stage(0, 0);
  __syncthreads();  // buf0 staged (implicit vmcnt(0))
  int cur = 0;
  for (int k0 = 0; k0 < 512; k0 += 32) {
    if (k0 + 32 < 512) stage(cur ^ 1, k0 + 32);  // in flight across compute
    half8 af[4], bf[4];
#pragma unroll
    for (int mf = 0; mf < 4; ++mf)
      af[mf] = *(const half8*)(As[cur] + (wm * 64 + mf * 16 + l15) * 32 + l4 * 8);
#pragma unroll
    for (int nf = 0; nf < 4; ++nf)
      bf[nf] = *(const half8*)(Bs[cur] + (wn * 64 + nf * 16 + l15) * 32 + l4 * 8);
#pragma unroll
    for (int mf = 0; mf < 4; ++mf)
#pragma unroll
      for (int nf = 0; nf < 4; ++nf)
        acc[mf][nf] = __builtin_amdgcn_mfma_f32_16x16x32_f16(af[mf], bf[nf], acc[mf][nf], 0, 0, 0);
    __syncthreads();  // drains next-tile loads; guards buf[cur] reuse
    cur ^= 1;
  }

  const int mbase = m0 + wm * 64;
  const int nbase = n0 + wn * 64;
  if (EPI == 0) {
#pragma unroll
    for (int nf = 0; nf < 4; ++nf) {
      const int n = nbase + nf * 16 + l15;
      if (n < 2048) {
        const float bias = (n < 512) ? qbias[n] : 0.0f;
#pragma unroll
        for (int mf = 0; mf < 4; ++mf) {
          const int mr = mbase + mf * 16 + l4 * 4;
#pragma unroll
          for (int j = 0; j < 4; ++j)
            Cqkv[(size_t)(mr + j) * 2048 + n] = (f16)(acc[mf][nf][j] + bias);
        }
      } else {
        const int i = n - 2048;
#pragma unroll
        for (int mf = 0; mf < 4; ++mf) {
          const int mr = mbase + mf * 16 + l4 * 4;
          const int nn = mr / 96;
          const int t = mr % 96;
          half4v v;
#pragma unroll
          for (int j = 0; j < 4; ++j) v[j] = (f16)acc[mf][nf][j];
          *(half4v*)(VT + ((size_t)nn * 512 + i) * 96 + t) = v;
        }
      }
    }
  } else {
#pragma unroll
    for (int nf = 0; nf < 4; ++nf) {
      const int m2 = nbase + nf * 16 + l15;
      const int bb = m2 / 24576;
      const int rem = m2 - bb * 24576;
      const int t = rem >> 8;
      const int hw = rem & 255;
      float* op = Out + ((size_t)bb * 512 * 96 + t) * 256 + hw;
#pragma unroll
      for (int mf = 0; mf < 4; ++mf) {
#pragma unroll
        for (int j = 0; j < 4; ++j) {
          const int d = mbase + mf * 16 + l4 * 4 + j;
          op[(size_t)d * 24576] = acc[mf][nf][j];
        }
      }
    }
  }
}

// ---------------------------------------------------------------------------
// Attention: one wave per (n, head). T=96 queries/keys, dh=64, local band s=3.
// QKV chunk rows m=(nn*96+t), cols: [0,512)=Q(+bias) [512,1024)=K
// [1024,1536)=KL [1536,2048)=VL. VT[nn][512][96] = V transposed.
__global__ __launch_bounds__(64) void attn_kernel(
    const f16* __restrict__ QKV, const f16* __restrict__ VT,
    f16* __restrict__ AO, int n0chunk) {
  const int nn = blockIdx.x >> 3;
  const int h = blockIdx.x & 7;
  const int lane = threadIdx.x;
  const int l15 = lane & 15, l4 = lane >> 4;
  const int nglob = n0chunk + nn;
  const int bb = nglob >> 8, hw = nglob & 255;

  __shared__ float locS[16][4];
  __shared__ float alS[16][4];
  __shared__ f16 pS[16][104];

  const f16* base = QKV + (size_t)nn * 96 * 2048;

  // K fragments (B operand of QK^T): col t' = l15 + nf*16, k = i
  half8 kb[6][2];
#pragma unroll
  for (int nf = 0; nf < 6; ++nf)
#pragma unroll
    for (int kg = 0; kg < 2; ++kg)
      kb[nf][kg] = *(const half8*)(base + (size_t)(nf * 16 + l15) * 2048 + 512 + h * 64 + kg * 32 + l4 * 8);

  // V fragments (B operand of P@V): col i = l15 + nf*16, k = g
  half8 vb[4][3];
  const f16* vtb = VT + ((size_t)nn * 512 + h * 64) * 96;
#pragma unroll
  for (int nf = 0; nf < 4; ++nf)
#pragma unroll
    for (int kg = 0; kg < 3; ++kg)
      vb[nf][kg] = *(const half8*)(vtb + (size_t)(nf * 16 + l15) * 96 + kg * 32 + l4 * 8);

  for (int mb = 0; mb < 6; ++mb) {
    const int t0 = mb * 16;

    // ---- local band logits (48 lanes, f32 dot-64) -> locS
    {
      const int tl = lane >> 2, sel = lane & 3;
      if (sel < 3) {
        const int t = t0 + tl;
        const int tp = t + sel - 1;
        float v = -INFINITY;
        if (tp >= 0 && tp < 96) {
          const f16* qr = base + (size_t)t * 2048 + h * 64;
          const f16* kr = base + (size_t)tp * 2048 + 1024 + h * 64;
          float a = 0.f;
#pragma unroll
          for (int w = 0; w < 8; ++w) {
            half8 qv = *(const half8*)(qr + w * 8);
            half8 kv = *(const half8*)(kr + w * 8);
#pragma unroll
            for (int e = 0; e < 8; ++e) a += (float)qv[e] * (float)kv[e];
          }
          v = a * 0.125f;
        }
        locS[tl][sel] = v;
      }
    }

    // ---- S = Q K^T (16 rows x 96 cols)
    floatx4 s[6] = {};
    half8 aq[2];
#pragma unroll
    for (int kg = 0; kg < 2; ++kg)
      aq[kg] = *(const half8*)(base + (size_t)(t0 + l15) * 2048 + h * 64 + kg * 32 + l4 * 8);
#pragma unroll
    for (int nf = 0; nf < 6; ++nf)
#pragma unroll
      for (int kg = 0; kg < 2; ++kg)
        s[nf] = __builtin_amdgcn_mfma_f32_16x16x32_f16(aq[kg], kb[nf][kg], s[nf], 0, 0, 0);
#pragma unroll
    for (int nf = 0; nf < 6; ++nf) s[nf] = s[nf] * 0.125f;

    __syncthreads();  // locS visible

    // ---- softmax per row (C-layout: row = l4*4+j, col = l15 + nf*16)
#pragma unroll
    for (int j = 0; j < 4; ++j) {
      const int row = l4 * 4 + j;
      float sv[6];
#pragma unroll
      for (int nf = 0; nf < 6; ++nf) sv[nf] = s[nf][j];
      float mx = sv[0];
#pragma unroll
      for (int nf = 1; nf < 6; ++nf) mx = fmaxf(mx, sv[nf]);
      for (int off = 1; off < 16; off <<= 1) mx = fmaxf(mx, __shfl_xor(mx, off, 64));
      const float l0 = locS[row][0], l1 = locS[row][1], l2 = locS[row][2];
      mx = fmaxf(mx, fmaxf(l0, fmaxf(l1, l2)));
      float e[6], sum = 0.f;
#pragma unroll
      for (int nf = 0; nf < 6; ++nf) {
        e[nf] = expf(sv[nf] - mx);
        sum += e[nf];
      }
      for (int off = 1; off < 16; off <<= 1) sum += __shfl_xor(sum, off, 64);
      const float e0 = expf(l0 - mx), e1 = expf(l1 - mx), e2 = expf(l2 - mx);
      sum += e0 + e1 + e2;
      const float rd = 1.0f / sum;
#pragma unroll
      for (int nf = 0; nf < 6; ++nf) pS[row][nf * 16 + l15] = (f16)(e[nf] * rd);
      if (l15 < 3) alS[row][l15] = (l15 == 0 ? e0 : (l15 == 1 ? e1 : e2)) * rd;
    }

    __syncthreads();  // pS / alS visible

    // ---- O = P @ V
    floatx4 o[4] = {};
    half8 pfr[3];
#pragma unroll
    for (int kg = 0; kg < 3; ++kg)
      pfr[kg] = *(const half8*)(&pS[l15][kg * 32 + l4 * 8]);
#pragma unroll
    for (int nf = 0; nf < 4; ++nf)
#pragma unroll
      for (int kg = 0; kg < 3; ++kg)
        o[nf] = __builtin_amdgcn_mfma_f32_16x16x32_f16(pfr[kg], vb[nf][kg], o[nf], 0, 0, 0);

    // ---- add local band (x_local) and store
#pragma unroll
    for (int nf = 0; nf < 4; ++nf) {
      const int col = h * 64 + nf * 16 + l15;
#pragma unroll
      for (int j = 0; j < 4; ++j) {
        const int row = l4 * 4 + j;
        const int t = t0 + row;
        float xv = o[nf][j];
#pragma unroll
        for (int sel = 0; sel < 3; ++sel) {
          const int tp = t + sel - 1;
          if (tp >= 0 && tp < 96) {
            xv += alS[row][sel] * (float)base[(size_t)tp * 2048 + 1536 + col];
          }
        }
        AO[((size_t)(bb * 96 + t) * 256 + hw) * 512 + col] = (f16)xv;
      }
    }
    __syncthreads();  // protect LDS for next m-block
  }
}

// ---------------------------------------------------------------------------
extern "C" void kernel_launch(void* const* d_in, const int* in_sizes, int n_in,
                              void* d_out, int out_size, void* d_ws, size_t ws_size,
                              hipStream_t stream) {
  (void)in_sizes; (void)n_in; (void)out_size;
  const float* x     = (const float*)d_in[0];
  const float* gamma = (const float*)d_in[1];
  const float* beta  = (const float*)d_in[2];
  const float* Wq    = (const float*)d_in[3];
  const float* Wk    = (const float*)d_in[4];
  const float* Wv    = (const float*)d_in[5];
  const float* Wkl   = (const float*)d_in[6];
  const float* Wvl   = (const float*)d_in[7];
  const float* Wo    = (const float*)d_in[8];
  const float* qb    = (const float*)d_in[9];
  float* out = (float*)d_out;

  char* ws = (char*)d_ws;
  size_t off = 0;
  auto alloc = [&](size_t bytes) -> void* {
    void* p = ws + off;
    off += (bytes + 255) & ~(size_t)255;
    return p;
  };
  f16* XN   = (f16*)alloc((size_t)MTOT * 512 * 2);
  f16* AO   = (f16*)alloc((size_t)MTOT * 512 * 2);
  f16* WQKV = (f16*)alloc((size_t)2560 * 512 * 2);
  f16* WOh  = (f16*)alloc((size_t)512 * 512 * 2);
  // chunking over n (512 total) to bound workspace
  int cn = 512;
  while (cn > 4 &&
         off + (size_t)cn * 96 * 2048 * 2 + 256 + (size_t)cn * 512 * 96 * 2 + 256 > ws_size)
    cn >>= 1;
  f16* QKVc = (f16*)alloc((size_t)cn * 96 * 2048 * 2);
  f16* VTc  = (f16*)alloc((size_t)cn * 512 * 96 * 2);

  wconv_kernel<<<5120, 256, 0, stream>>>(Wq, Wk, Wv, Wkl, Wvl, Wo, WQKV, WOh);
  ln_kernel<<<768, 256, 0, stream>>>(x, gamma, beta, XN);

  const int nch = 512 / cn;
  for (int c = 0; c < nch; ++c) {
    const int ng1 = (cn * 96 / 128) * 20;  // multiple of 8 for all cn >= 8
    gemm_kernel<0><<<ng1, 256, 0, stream>>>(XN + (size_t)c * cn * 96 * 512, WQKV,
                                            QKVc, VTc, qb, nullptr);
    attn_kernel<<<cn * 8, 64, 0, stream>>>(QKVc, VTc, AO, c * cn);
  }
  gemm_kernel<1><<<1536, 256, 0, stream>>>(WOh, AO, nullptr, nullptr, nullptr, out);
}

// Round 3
// 461.148 us; speedup vs baseline: 1.3121x; 1.1687x over previous
//
#include <hip/hip_runtime.h>
#include <hip/hip_fp16.h>
#include <cstdint>
#include <cstddef>

typedef _Float16 f16;
typedef _Float16 half8 __attribute__((ext_vector_type(8)));
typedef _Float16 half4v __attribute__((ext_vector_type(4)));
typedef float floatx4 __attribute__((ext_vector_type(4)));

#define MTOT 49152  // B*T*HW rows total (=2*96*256), also = N_TOT*T

// ---------------------------------------------------------------------------
// async global->LDS, 16B per lane
__device__ __forceinline__ void gload_lds16(const f16* g, f16* l) {
  __builtin_amdgcn_global_load_lds((const __attribute__((address_space(1))) void*)g,
                                   (__attribute__((address_space(3))) void*)l, 16, 0, 0);
}

// unaligned-tolerant 16B load (addr may be only 4B-aligned)
__device__ __forceinline__ half8 load_h8u(const f16* p) {
  half8 v;
  __builtin_memcpy(&v, p, 16);
  return v;
}

// ---------------------------------------------------------------------------
// Convert weights fp32 -> f16. WQKV rows: [0,512)=Wq [512,1024)=Wk
// [1024,1536)=Wkl [1536,2048)=Wvl [2048,2560)=Wv.  WO separate.
__global__ __launch_bounds__(256) void wconv_kernel(
    const float* __restrict__ Wq, const float* __restrict__ Wk,
    const float* __restrict__ Wv, const float* __restrict__ Wkl,
    const float* __restrict__ Wvl, const float* __restrict__ Wo,
    f16* __restrict__ WQKV, f16* __restrict__ WO) {
  int idx = blockIdx.x * 256 + threadIdx.x;
  if (idx < 2560 * 512) {
    int row = idx >> 9;
    int col = idx & 511;
    int seg = row >> 9;
    int r = row & 511;
    const float* src;
    switch (seg) {
      case 0: src = Wq; break;
      case 1: src = Wk; break;
      case 2: src = Wkl; break;
      case 3: src = Wvl; break;
      default: src = Wv; break;
    }
    WQKV[idx] = (f16)src[r * 512 + col];
  }
  if (idx < 512 * 512) WO[idx] = (f16)Wo[idx];
}

// ---------------------------------------------------------------------------
// LayerNorm over D. x layout (B=2, D=512, T=96, HW=256).
// Output XN f16 row-major [m][512], m = (b*256+hw)*96 + t.
__global__ __launch_bounds__(256) void ln_kernel(
    const float* __restrict__ x, const float* __restrict__ gamma,
    const float* __restrict__ beta, f16* __restrict__ XN) {
  const int hwg = blockIdx.x & 3;
  const int t   = (blockIdx.x >> 2) % 96;
  const int b   = blockIdx.x / (4 * 96);
  const int lhw = threadIdx.x & 63;
  const int dg  = threadIdx.x >> 6;
  const int hw  = hwg * 64 + lhw;
  const float* xp = x + (size_t)b * 512 * 24576 + (size_t)t * 256 + hw;

  float s = 0.f, s2 = 0.f;
  for (int d = dg * 128; d < dg * 128 + 128; ++d) {
    float v = xp[(size_t)d * 24576];
    s += v;
    s2 += v * v;
  }
  __shared__ float S1[4][64], S2[4][64];
  S1[dg][lhw] = s;
  S2[dg][lhw] = s2;
  __syncthreads();
  s  = S1[0][lhw] + S1[1][lhw] + S1[2][lhw] + S1[3][lhw];
  s2 = S2[0][lhw] + S2[1][lhw] + S2[2][lhw] + S2[3][lhw];
  const float mean = s * (1.f / 512.f);
  float var = s2 * (1.f / 512.f) - mean * mean;
  var = fmaxf(var, 0.f);
  const float rstd = rsqrtf(var + 1e-6f);
  const int n = b * 256 + hw;
  f16* outp = XN + ((size_t)n * 96 + t) * 512;
  for (int d0 = dg * 128; d0 < dg * 128 + 128; d0 += 8) {
    half8 buf;
#pragma unroll
    for (int j = 0; j < 8; ++j) {
      float v = xp[(size_t)(d0 + j) * 24576];
      buf[j] = (f16)((v - mean) * rstd * gamma[d0 + j] + beta[d0 + j]);
    }
    *(half8*)(outp + d0) = buf;
  }
}

// ---------------------------------------------------------------------------
// Tiled f16 GEMM: C[m][n] = sum_k A[m][k]*B[n][k]  (K=512 fixed)
// BM=BN=128, BK=32, 4 waves (2x2), wave tile 64x64 of 16x16x32 MFMA.
// Double-buffered LDS, single barrier per K-step.
// EPI==0 epilogue: n<1536 -> QKV' (stride 1536, Q gets bias);
//                  1536..2048 -> VLT transposed; >=2048 -> VT transposed.
// EPI==1 epilogue: fp32 out in (B,D,T,HW) layout.
template <int EPI>
__global__ __launch_bounds__(256) void gemm_kernel(
    const f16* __restrict__ A, const f16* __restrict__ B,
    f16* __restrict__ Cqkv, f16* __restrict__ VT, f16* __restrict__ VLT,
    const float* __restrict__ qbias, float* __restrict__ Out) {
  __shared__ f16 As[2][128 * 32];
  __shared__ f16 Bs[2][128 * 32];

  const int lin = blockIdx.x;
  const int cpx = (int)gridDim.x >> 3;  // per-XCD chunk (gridDim.x % 8 == 0)
  const int o = (lin & 7) * cpx + (lin >> 3);
  int mt, nt;
  if (EPI == 0) {
    mt = o / 20;
    nt = o % 20;
  } else {
    nt = o >> 2;
    mt = o & 3;
  }
  const int m0 = mt * 128;
  const int n0 = nt * 128;
  const int tid = threadIdx.x;
  const int lane = tid & 63;
  const int wid = tid >> 6;
  const int wm = wid >> 1, wn = wid & 1;
  const int l15 = lane & 15, l4 = lane >> 4;

  floatx4 acc[4][4] = {};

  const int srow = tid >> 2;
  const int skp = (tid & 3) * 8;
  const f16* ap = A + (size_t)(m0 + srow) * 512 + skp;
  const f16* bp = B + (size_t)(n0 + srow) * 512 + skp;

  auto stage = [&](int buf, int k0) {
    f16* asl = As[buf] + tid * 8;
    f16* bsl = Bs[buf] + tid * 8;
    gload_lds16(ap + k0, asl);
    gload_lds16(ap + (size_t)64 * 512 + k0, asl + 2048);
    gload_lds16(bp + k0, bsl);
    gload_lds16(bp + (size_t)64 * 512 + k0, bsl + 2048);
  };

  stage(0, 0);
  __syncthreads();
  int cur = 0;
  for (int k0 = 0; k0 < 512; k0 += 32) {
    if (k0 + 32 < 512) stage(cur ^ 1, k0 + 32);
    half8 af[4], bf[4];
#pragma unroll
    for (int mf = 0; mf < 4; ++mf)
      af[mf] = *(const half8*)(As[cur] + (wm * 64 + mf * 16 + l15) * 32 + l4 * 8);
#pragma unroll
    for (int nf = 0; nf < 4; ++nf)
      bf[nf] = *(const half8*)(Bs[cur] + (wn * 64 + nf * 16 + l15) * 32 + l4 * 8);
#pragma unroll
    for (int mf = 0; mf < 4; ++mf)
#pragma unroll
      for (int nf = 0; nf < 4; ++nf)
        acc[mf][nf] = __builtin_amdgcn_mfma_f32_16x16x32_f16(af[mf], bf[nf], acc[mf][nf], 0, 0, 0);
    __syncthreads();
    cur ^= 1;
  }

  const int mbase = m0 + wm * 64;
  const int nbase = n0 + wn * 64;
  if (EPI == 0) {
#pragma unroll
    for (int nf = 0; nf < 4; ++nf) {
      const int n = nbase + nf * 16 + l15;
      if (n < 1536) {
        const float bias = (n < 512) ? qbias[n] : 0.0f;
#pragma unroll
        for (int mf = 0; mf < 4; ++mf) {
          const int mr = mbase + mf * 16 + l4 * 4;
#pragma unroll
          for (int j = 0; j < 4; ++j)
            Cqkv[(size_t)(mr + j) * 1536 + n] = (f16)(acc[mf][nf][j] + bias);
        }
      } else {
        f16* dst = (n < 2048) ? VLT : VT;
        const int i = (n < 2048) ? (n - 1536) : (n - 2048);
#pragma unroll
        for (int mf = 0; mf < 4; ++mf) {
          const int mr = mbase + mf * 16 + l4 * 4;
          const int nn = mr / 96;
          const int t = mr % 96;
          half4v v;
#pragma unroll
          for (int j = 0; j < 4; ++j) v[j] = (f16)acc[mf][nf][j];
          *(half4v*)(dst + ((size_t)nn * 512 + i) * 96 + t) = v;
        }
      }
    }
  } else {
#pragma unroll
    for (int nf = 0; nf < 4; ++nf) {
      const int m2 = nbase + nf * 16 + l15;
      const int bb = m2 / 24576;
      const int rem = m2 - bb * 24576;
      const int t = rem >> 8;
      const int hw = rem & 255;
      float* op = Out + ((size_t)bb * 512 * 96 + t) * 256 + hw;
#pragma unroll
      for (int mf = 0; mf < 4; ++mf) {
#pragma unroll
        for (int j = 0; j < 4; ++j) {
          const int d = mbase + mf * 16 + l4 * 4 + j;
          op[(size_t)d * 24576] = acc[mf][nf][j];
        }
      }
    }
  }
}

// ---------------------------------------------------------------------------
// Attention: one wave per (nn, head, mb-pair). T=96, dh=64, band s=3.
// QKV' rows m=(nn*96+t), cols: [0,512)=Q(+bias) [512,1024)=K [1024,1536)=KL.
// VT[nn][512][96]=V^T, VLT[nn][512][96]=VL^T.
// Band logits via two extra Q*KL window MFMAs; band PV via pS2[16][32] MFMA.
__global__ __launch_bounds__(64) void attn_kernel(
    const f16* __restrict__ QKV, const f16* __restrict__ VT,
    const f16* __restrict__ VLT, f16* __restrict__ AO, int n0chunk) {
  const int nn = blockIdx.x >> 3;
  const int h = blockIdx.x & 7;
  const int mb0 = blockIdx.y * 2;
  const int lane = threadIdx.x;
  const int l15 = lane & 15, l4 = lane >> 4;
  const int nglob = n0chunk + nn;
  const int bb = nglob >> 8, hw = nglob & 255;

  __shared__ __align__(16) float locS[16][4];
  __shared__ __align__(16) f16 pS[16][104];
  __shared__ __align__(16) f16 pS2[16][40];

  const f16* base = QKV + (size_t)nn * 96 * 1536;
  const f16* vtb  = VT  + ((size_t)nn * 512 + h * 64) * 96;
  const f16* vltb = VLT + ((size_t)nn * 512 + h * 64) * 96;

  // K fragments (persistent): col t' = l15 + nf*16, k-contiguous
  half8 kb[6][2];
#pragma unroll
  for (int nf = 0; nf < 6; ++nf)
#pragma unroll
    for (int kg = 0; kg < 2; ++kg)
      kb[nf][kg] = *(const half8*)(base + (size_t)(nf * 16 + l15) * 1536 + 512 + h * 64 + kg * 32 + l4 * 8);

  for (int mb = mb0; mb < mb0 + 2; ++mb) {
    const int t0 = mb * 16;
    const int tb = (t0 >= 2) ? (t0 - 2) : 0;  // even window base for VLT reads
    const int d0 = t0 - 1 - tb;               // -1 (t0==0) or +1

    // ---- Q and KL-window fragment loads
    half8 aq[2], kl1[2], kl2[2];
    {
      int r1 = t0 - 1 + l15; if (r1 < 0) r1 = 0;
      int r2 = t0 + 1 + l15; if (r2 > 95) r2 = 95;
#pragma unroll
      for (int kg = 0; kg < 2; ++kg) {
        aq[kg]  = *(const half8*)(base + (size_t)(t0 + l15) * 1536 + h * 64 + kg * 32 + l4 * 8);
        kl1[kg] = *(const half8*)(base + (size_t)r1 * 1536 + 1024 + h * 64 + kg * 32 + l4 * 8);
        kl2[kg] = *(const half8*)(base + (size_t)r2 * 1536 + 1024 + h * 64 + kg * 32 + l4 * 8);
      }
    }

    // ---- S = Q K^T (16x96) and band windows SL1/SL2 (16x16 each)
    floatx4 s[6] = {};
    floatx4 sl1 = {}, sl2 = {};
#pragma unroll
    for (int nf = 0; nf < 6; ++nf)
#pragma unroll
      for (int kg = 0; kg < 2; ++kg)
        s[nf] = __builtin_amdgcn_mfma_f32_16x16x32_f16(aq[kg], kb[nf][kg], s[nf], 0, 0, 0);
#pragma unroll
    for (int kg = 0; kg < 2; ++kg) {
      sl1 = __builtin_amdgcn_mfma_f32_16x16x32_f16(aq[kg], kl1[kg], sl1, 0, 0, 0);
      sl2 = __builtin_amdgcn_mfma_f32_16x16x32_f16(aq[kg], kl2[kg], sl2, 0, 0, 0);
    }

    // ---- issue PV operand loads early (consumed after softmax)
    half8 vb[4][3], vlb[4];
#pragma unroll
    for (int nf = 0; nf < 4; ++nf) {
#pragma unroll
      for (int kg = 0; kg < 3; ++kg)
        vb[nf][kg] = *(const half8*)(vtb + (size_t)(nf * 16 + l15) * 96 + kg * 32 + l4 * 8);
      vlb[nf] = load_h8u(vltb + (size_t)(nf * 16 + l15) * 96 + tb + l4 * 8);
    }

    // ---- zero pS2, extract band logits -> locS
    {
      half8 z = {};
      f16* pz = &pS2[0][0];
      *(half8*)(pz + lane * 8) = z;
      if (lane < 16) *(half8*)(pz + 512 + lane * 8) = z;
    }
#pragma unroll
    for (int j = 0; j < 4; ++j) {
      const int r = l4 * 4 + j;
      const int s1i = l15 - r;
      if (s1i >= 0 && s1i < 3) locS[r][s1i] = sl1[j] * 0.125f;
      const int s2i = l15 + 2 - r;
      if (l15 >= 14 && s2i >= 0 && s2i < 3) locS[r][s2i] = sl2[j] * 0.125f;
    }
    __syncthreads();

    // ---- softmax per row (C-layout: row = l4*4+j, col = l15 + nf*16)
#pragma unroll
    for (int j = 0; j < 4; ++j) {
      const int row = l4 * 4 + j;
      float sv[6];
#pragma unroll
      for (int nf = 0; nf < 6; ++nf) sv[nf] = s[nf][j] * 0.125f;
      float mx = sv[0];
#pragma unroll
      for (int nf = 1; nf < 6; ++nf) mx = fmaxf(mx, sv[nf]);
      for (int off = 1; off < 16; off <<= 1) mx = fmaxf(mx, __shfl_xor(mx, off, 64));
      const float l0 = (t0 + row >= 1)  ? locS[row][0] : -__builtin_inff();
      const float l1 = locS[row][1];
      const float l2 = (t0 + row <= 94) ? locS[row][2] : -__builtin_inff();
      mx = fmaxf(mx, fmaxf(l0, fmaxf(l1, l2)));
      float e[6], sum = 0.f;
#pragma unroll
      for (int nf = 0; nf < 6; ++nf) {
        e[nf] = expf(sv[nf] - mx);
        sum += e[nf];
      }
      for (int off = 1; off < 16; off <<= 1) sum += __shfl_xor(sum, off, 64);
      const float e0 = expf(l0 - mx), e1 = expf(l1 - mx), e2 = expf(l2 - mx);
      sum += e0 + e1 + e2;
      const float rd = 1.0f / sum;
#pragma unroll
      for (int nf = 0; nf < 6; ++nf) pS[row][nf * 16 + l15] = (f16)(e[nf] * rd);
      if (l15 < 3) {
        const int w = row + l15 + d0;
        const float ev = (l15 == 0) ? e0 : ((l15 == 1) ? e1 : e2);
        if (w >= 0) pS2[row][w] = (f16)(ev * rd);
      }
    }
    __syncthreads();

    // ---- O = P @ V  +  P2 @ VL-window
    floatx4 o[4] = {};
    half8 pfr[3];
#pragma unroll
    for (int kg = 0; kg < 3; ++kg)
      pfr[kg] = *(const half8*)(&pS[l15][kg * 32 + l4 * 8]);
    half8 pf2 = *(const half8*)(&pS2[l15][l4 * 8]);
#pragma unroll
    for (int nf = 0; nf < 4; ++nf) {
#pragma unroll
      for (int kg = 0; kg < 3; ++kg)
        o[nf] = __builtin_amdgcn_mfma_f32_16x16x32_f16(pfr[kg], vb[nf][kg], o[nf], 0, 0, 0);
      o[nf] = __builtin_amdgcn_mfma_f32_16x16x32_f16(pf2, vlb[nf], o[nf], 0, 0, 0);
    }

    // ---- store
#pragma unroll
    for (int nf = 0; nf < 4; ++nf) {
      const int col = h * 64 + nf * 16 + l15;
#pragma unroll
      for (int j = 0; j < 4; ++j) {
        const int t = t0 + l4 * 4 + j;
        AO[((size_t)(bb * 96 + t) * 256 + hw) * 512 + col] = (f16)o[nf][j];
      }
    }
    __syncthreads();  // protect pS/pS2/locS before next m-block
  }
}

// ---------------------------------------------------------------------------
extern "C" void kernel_launch(void* const* d_in, const int* in_sizes, int n_in,
                              void* d_out, int out_size, void* d_ws, size_t ws_size,
                              hipStream_t stream) {
  (void)in_sizes; (void)n_in; (void)out_size;
  const float* x     = (const float*)d_in[0];
  const float* gamma = (const float*)d_in[1];
  const float* beta  = (const float*)d_in[2];
  const float* Wq    = (const float*)d_in[3];
  const float* Wk    = (const float*)d_in[4];
  const float* Wv    = (const float*)d_in[5];
  const float* Wkl   = (const float*)d_in[6];
  const float* Wvl   = (const float*)d_in[7];
  const float* Wo    = (const float*)d_in[8];
  const float* qb    = (const float*)d_in[9];
  float* out = (float*)d_out;

  char* ws = (char*)d_ws;
  size_t off = 0;
  auto alloc = [&](size_t bytes) -> void* {
    void* p = ws + off;
    off += (bytes + 255) & ~(size_t)255;
    return p;
  };
  f16* XN   = (f16*)alloc((size_t)MTOT * 512 * 2);
  f16* AO   = (f16*)alloc((size_t)MTOT * 512 * 2);
  f16* WQKV = (f16*)alloc((size_t)2560 * 512 * 2);
  f16* WOh  = (f16*)alloc((size_t)512 * 512 * 2);
  // chunking over n (512 total) to bound workspace
  int cn = 512;
  while (cn > 4 &&
         off + (size_t)cn * 96 * 1536 * 2 + 256 + (size_t)cn * 512 * 96 * 2 + 256 +
                 (size_t)cn * 512 * 96 * 2 + 512 > ws_size)
    cn >>= 1;
  f16* QKVc = (f16*)alloc((size_t)cn * 96 * 1536 * 2);
  f16* VTc  = (f16*)alloc((size_t)cn * 512 * 96 * 2);
  f16* VLTc = (f16*)alloc((size_t)cn * 512 * 96 * 2 + 256);  // +guard

  wconv_kernel<<<5120, 256, 0, stream>>>(Wq, Wk, Wv, Wkl, Wvl, Wo, WQKV, WOh);
  ln_kernel<<<768, 256, 0, stream>>>(x, gamma, beta, XN);
  // zero the VLT guard so out-of-window fragment reads stay finite
  hipMemsetAsync((char*)VLTc + (size_t)cn * 512 * 96 * 2, 0, 256, stream);

  const int nch = 512 / cn;
  for (int c = 0; c < nch; ++c) {
    const int ng1 = (cn * 96 / 128) * 20;  // multiple of 8 for all cn >= 8
    gemm_kernel<0><<<ng1, 256, 0, stream>>>(XN + (size_t)c * cn * 96 * 512, WQKV,
                                            QKVc, VTc, VLTc, qb, nullptr);
    attn_kernel<<<dim3(cn * 8, 3), 64, 0, stream>>>(QKVc, VTc, VLTc, AO, c * cn);
  }
  gemm_kernel<1><<<1536, 256, 0, stream>>>(WOh, AO, nullptr, nullptr, nullptr, nullptr, out);
}